// Round 1
// baseline (1178.088 us; speedup 1.0000x reference)
//
#include <hip/hip_runtime.h>

typedef __bf16 bf16_t;
typedef bf16_t bf16x8 __attribute__((ext_vector_type(8)));
typedef bf16_t bf16x4 __attribute__((ext_vector_type(4)));
typedef float  f32x4  __attribute__((ext_vector_type(4)));

typedef const __attribute__((address_space(1))) void* gptr_t;
typedef __attribute__((address_space(3))) void* sptr_t;

// ---------------- constants ----------------
// B=8, L=4096, D=1024, M=B*L=32768
#define BATCH 8
#define SEQL  4096
#define DIM   1024
#define MROWS 32768

__device__ __forceinline__ float sigmoidf_(float v) {
    return 1.0f / (1.0f + __expf(-v));
}

// ---------------- transpose + cast fp32 (K,N) -> bf16 (N,K) ----------------
__global__ void transpose_cast(const float* __restrict__ W, bf16_t* __restrict__ WT,
                               int K, int N) {
    __shared__ float s[32][33];
    int tx = threadIdx.x, ty = threadIdx.y;
    int x = blockIdx.x * 32 + tx;   // N index
    int y = blockIdx.y * 32 + ty;   // K index
    s[ty][tx] = W[(size_t)y * N + x];
    __syncthreads();
    int n = blockIdx.x * 32 + ty;
    int k = blockIdx.y * 32 + tx;
    WT[(size_t)n * K + k] = (bf16_t)s[tx][ty];
}

// ---------------- cast fp32 -> bf16 (vectorized x4) ----------------
__global__ void cast_bf16(const float* __restrict__ in, bf16_t* __restrict__ out) {
    size_t i = (size_t)blockIdx.x * 256 + threadIdx.x;
    float4 v = ((const float4*)in)[i];
    bf16x4 o = { (bf16_t)v.x, (bf16_t)v.y, (bf16_t)v.z, (bf16_t)v.w };
    ((bf16x4*)out)[i] = o;
}

// ---------------- prefix-mean scan (3 phases, chunk=64) ----------------
__global__ void scan_chunks(const float* __restrict__ x, float* __restrict__ cs) {
    int t = threadIdx.x;
    int bx = blockIdx.x;            // 8*64*4 = 2048
    int dblk = bx & 3;
    int c = (bx >> 2) & 63;
    int b = bx >> 8;
    int d = (dblk << 8) + t;
    const float* p = x + ((size_t)b * SEQL + (size_t)c * 64) * DIM + d;
    float s = 0.f;
#pragma unroll 8
    for (int j = 0; j < 64; ++j) s += p[(size_t)j * DIM];
    cs[(size_t)((b << 6) + c) * DIM + d] = s;
}

__global__ void scan_prefix(float* __restrict__ cs) {
    int t = blockIdx.x * 256 + threadIdx.x;   // 8192 threads
    int b = t >> 10, d = t & 1023;
    float run = 0.f;
    for (int c = 0; c < 64; ++c) {
        size_t idx = (size_t)((b << 6) + c) * DIM + d;
        float v = cs[idx];
        cs[idx] = run;
        run += v;
    }
}

__global__ void scan_final(const float* __restrict__ x, const float* __restrict__ cs,
                           float* __restrict__ avg) {
    int t = threadIdx.x;
    int bx = blockIdx.x;
    int dblk = bx & 3;
    int c = (bx >> 2) & 63;
    int b = bx >> 8;
    int d = (dblk << 8) + t;
    size_t base = ((size_t)b * SEQL + (size_t)c * 64) * DIM + d;
    const float* p = x + base;
    float* q = avg + base;
    float run = cs[(size_t)((b << 6) + c) * DIM + d];
#pragma unroll 8
    for (int j = 0; j < 64; ++j) {
        run += p[(size_t)j * DIM];
        int l = c * 64 + j;
        q[(size_t)j * DIM] = run / (float)(l + 1);
    }
}

// ---------------- LayerNorm over D=1024, one wave per row ----------------
__global__ void ln_kernel(const float* __restrict__ avg, const float* __restrict__ g,
                          const float* __restrict__ bb, bf16_t* __restrict__ h) {
    int wave = threadIdx.x >> 6, lane = threadIdx.x & 63;
    size_t row = (size_t)blockIdx.x * 4 + wave;
    const float* p = avg + row * DIM;
    float4 v[4];
    float s = 0.f, sq = 0.f;
#pragma unroll
    for (int i = 0; i < 4; ++i) {
        v[i] = ((const float4*)p)[lane * 4 + i];
        s  += v[i].x + v[i].y + v[i].z + v[i].w;
        sq += v[i].x * v[i].x + v[i].y * v[i].y + v[i].z * v[i].z + v[i].w * v[i].w;
    }
#pragma unroll
    for (int off = 32; off; off >>= 1) {
        s  += __shfl_xor(s, off);
        sq += __shfl_xor(sq, off);
    }
    float mu  = s * (1.f / DIM);
    float var = sq * (1.f / DIM) - mu * mu;
    var = var < 0.f ? 0.f : var;
    float rs = 1.0f / sqrtf(var + 1e-6f);
    bf16_t* hp = h + row * DIM;
#pragma unroll
    for (int i = 0; i < 4; ++i) {
        int c0 = lane * 16 + i * 4;
        float vv[4] = { v[i].x, v[i].y, v[i].z, v[i].w };
        bf16x4 o;
#pragma unroll
        for (int j = 0; j < 4; ++j) {
            int c = c0 + j;
            o[j] = (bf16_t)((vv[j] - mu) * rs * g[c] + bb[c]);
        }
        *(bf16x4*)(hp + c0) = o;
    }
}

// ---------------- MFMA bf16 GEMM, 128x128 tile, BK=64 (m97 structure) -------
// C = A @ Bt^T ; A: M x K (row stride kSplit per source), Bt: N x K row-major.
// A source = A0 for k < kSplit, A1 for k >= kSplit (concat along K).
// EPI 1: outb = bf16(relu(acc + bias[n]))
// EPI 2: v = acc + bias[n] + addsrc[idx]; outf = v; outb = bf16(v)
// EPI 3: outb = bf16(acc + bias[n])
template <int EPI>
__global__ __launch_bounds__(256) void gemm_bt(
    const bf16_t* __restrict__ A0, const bf16_t* __restrict__ A1, int kSplit,
    const bf16_t* __restrict__ Bt, int M, int N, int K,
    const float* __restrict__ bias, const float* __restrict__ addsrc,
    float* __restrict__ outf, bf16_t* __restrict__ outb) {
    __shared__ bf16_t As[128 * 64];
    __shared__ bf16_t Bs[128 * 64];
    const int tid = threadIdx.x;
    const int wave = tid >> 6, lane = tid & 63;
    const int nBlocks = N >> 7;
    const int m0 = (int)(blockIdx.x / nBlocks) << 7;
    const int n0 = (int)(blockIdx.x % nBlocks) << 7;
    const int wm = (wave & 1) << 6;
    const int wn = (wave >> 1) << 6;
    const int lrow16 = lane & 15;
    const int lk8 = (lane >> 4) << 3;

    f32x4 acc[4][4] = {};

    for (int k0 = 0; k0 < K; k0 += 64) {
        __syncthreads();
        const bf16_t* Asrc;
        int ak0;
        if (k0 < kSplit) { Asrc = A0; ak0 = k0; }
        else             { Asrc = A1; ak0 = k0 - kSplit; }
#pragma unroll
        for (int rd = 0; rd < 4; ++rd) {
            int ci = tid + rd * 256;
            int row = ci >> 3, ch = ci & 7;
            const bf16_t* g = Asrc + (size_t)(m0 + row) * kSplit + ak0 + (ch << 3);
            bf16_t* sb = &As[(size_t)((rd << 8) + (wave << 6)) * 8];
            __builtin_amdgcn_global_load_lds((gptr_t)g, (sptr_t)sb, 16, 0, 0);
        }
#pragma unroll
        for (int rd = 0; rd < 4; ++rd) {
            int ci = tid + rd * 256;
            int row = ci >> 3, ch = ci & 7;
            const bf16_t* g = Bt + (size_t)(n0 + row) * K + k0 + (ch << 3);
            bf16_t* sb = &Bs[(size_t)((rd << 8) + (wave << 6)) * 8];
            __builtin_amdgcn_global_load_lds((gptr_t)g, (sptr_t)sb, 16, 0, 0);
        }
        __syncthreads();
#pragma unroll
        for (int kk = 0; kk < 64; kk += 32) {
            bf16x8 af[4], bfv[4];
#pragma unroll
            for (int mi = 0; mi < 4; ++mi)
                af[mi] = *(const bf16x8*)&As[(wm + mi * 16 + lrow16) * 64 + kk + lk8];
#pragma unroll
            for (int ni = 0; ni < 4; ++ni)
                bfv[ni] = *(const bf16x8*)&Bs[(wn + ni * 16 + lrow16) * 64 + kk + lk8];
#pragma unroll
            for (int mi = 0; mi < 4; ++mi)
#pragma unroll
                for (int ni = 0; ni < 4; ++ni)
                    acc[mi][ni] = __builtin_amdgcn_mfma_f32_16x16x32_bf16(
                        af[mi], bfv[ni], acc[mi][ni], 0, 0, 0);
        }
    }

    const int erow = (lane >> 4) << 2;
#pragma unroll
    for (int mi = 0; mi < 4; ++mi) {
#pragma unroll
        for (int ni = 0; ni < 4; ++ni) {
            int col = n0 + wn + ni * 16 + lrow16;
            float bcol = bias[col];
#pragma unroll
            for (int r = 0; r < 4; ++r) {
                int row = m0 + wm + mi * 16 + erow + r;
                size_t idx = (size_t)row * N + col;
                float v = acc[mi][ni][r];
                if (EPI == 1) {
                    v += bcol;
                    v = v > 0.f ? v : 0.f;
                    outb[idx] = (bf16_t)v;
                } else if (EPI == 2) {
                    v += bcol + addsrc[idx];
                    outf[idx] = v;
                    outb[idx] = (bf16_t)v;
                } else {
                    v += bcol;
                    outb[idx] = (bf16_t)v;
                }
            }
        }
    }
}

// ---------------- final gating ----------------
__global__ void gate_kernel(const float* __restrict__ x, const float* __restrict__ ao,
                            const bf16_t* __restrict__ gates, float* __restrict__ out) {
    size_t i4 = (size_t)blockIdx.x * 256 + threadIdx.x;   // float4 index
    size_t base = i4 * 4;
    size_t row = base >> 10;
    int d = (int)(base & 1023);
    float4 xv = ((const float4*)x)[i4];
    float4 av = ((const float4*)ao)[i4];
    const bf16_t* gp = gates + row * 2048 + d;
    bf16x4 ig = *(const bf16x4*)gp;
    bf16x4 fg = *(const bf16x4*)(gp + 1024);
    float4 o;
    o.x = sigmoidf_((float)ig[0]) * xv.x + sigmoidf_((float)fg[0]) * av.x;
    o.y = sigmoidf_((float)ig[1]) * xv.y + sigmoidf_((float)fg[1]) * av.y;
    o.z = sigmoidf_((float)ig[2]) * xv.z + sigmoidf_((float)fg[2]) * av.z;
    o.w = sigmoidf_((float)ig[3]) * xv.w + sigmoidf_((float)fg[3]) * av.w;
    ((float4*)out)[i4] = o;
}

// ---------------- launch ----------------
extern "C" void kernel_launch(void* const* d_in, const int* in_sizes, int n_in,
                              void* d_out, int out_size, void* d_ws, size_t ws_size,
                              hipStream_t stream) {
    const float* inp  = (const float*)d_in[0];
    const float* w1   = (const float*)d_in[1];
    const float* b1   = (const float*)d_in[2];
    const float* w2   = (const float*)d_in[3];
    const float* b2   = (const float*)d_in[4];
    const float* ln_g = (const float*)d_in[5];
    const float* ln_b = (const float*)d_in[6];
    const float* wg   = (const float*)d_in[7];
    const float* bg   = (const float*)d_in[8];
    float* out = (float*)d_out;

    char* w = (char*)d_ws;
    float*  avg    = (float*)w;   w += (size_t)MROWS * DIM * 4;       // 128 MB
    float*  avgout = (float*)w;   w += (size_t)MROWS * DIM * 4;       // 128 MB
    bf16_t* xb     = (bf16_t*)w;  w += (size_t)MROWS * DIM * 2;       // 64 MB
    bf16_t* hb     = (bf16_t*)w;  w += (size_t)MROWS * DIM * 2;       // 64 MB
    bf16_t* interb = (bf16_t*)w;  w += (size_t)MROWS * DIM * 2;       // 64 MB
    bf16_t* w1t    = (bf16_t*)w;  w += (size_t)DIM * DIM * 2;         // 2 MB
    bf16_t* w2t    = (bf16_t*)w;  w += (size_t)DIM * DIM * 2;         // 2 MB
    bf16_t* wgt    = (bf16_t*)w;  w += (size_t)2 * DIM * 2 * DIM * 2; // 8 MB
    float*  csum   = (float*)w;   w += (size_t)BATCH * 64 * DIM * 4;  // 2 MB
    bf16_t* gates  = (bf16_t*)avg;  // alias: avg dead after GEMM2, gates needs 128 MB
    bf16_t* aob    = hb;            // alias: h dead after GEMM1

    // weight transposes (fp32 KxN -> bf16 NxK)
    transpose_cast<<<dim3(32, 32), dim3(32, 32), 0, stream>>>(w1, w1t, DIM, DIM);
    transpose_cast<<<dim3(32, 32), dim3(32, 32), 0, stream>>>(w2, w2t, DIM, DIM);
    transpose_cast<<<dim3(64, 64), dim3(32, 32), 0, stream>>>(wg, wgt, 2 * DIM, 2 * DIM);

    // inputs -> bf16 (for GEMM3's A first half)
    cast_bf16<<<32768, 256, 0, stream>>>(inp, xb);

    // prefix-mean scan
    scan_chunks<<<2048, 256, 0, stream>>>(inp, csum);
    scan_prefix<<<32, 256, 0, stream>>>(csum);
    scan_final<<<2048, 256, 0, stream>>>(inp, csum, avg);

    // layernorm -> h (bf16)
    ln_kernel<<<8192, 256, 0, stream>>>(avg, ln_g, ln_b, hb);

    // GEMM1: inter = relu(h @ w1 + b1)
    gemm_bt<1><<<(MROWS / 128) * (DIM / 128), 256, 0, stream>>>(
        hb, nullptr, DIM, w1t, MROWS, DIM, DIM, b1, nullptr, nullptr, interb);

    // GEMM2: avg_out = inter @ w2 + b2 + avg  (fp32 + bf16 stores)
    gemm_bt<2><<<(MROWS / 128) * (DIM / 128), 256, 0, stream>>>(
        interb, nullptr, DIM, w2t, MROWS, DIM, DIM, b2, avg, avgout, aob);

    // GEMM3: gates = concat(x, avg_out) @ wg + bg  (bf16 store)
    gemm_bt<3><<<(MROWS / 128) * (2 * DIM / 128), 256, 0, stream>>>(
        xb, aob, DIM, wgt, MROWS, 2 * DIM, 2 * DIM, bg, nullptr, nullptr, gates);

    // out = sigmoid(ig)*x + sigmoid(fg)*avg_out
    gate_kernel<<<32768, 256, 0, stream>>>(inp, avgout, gates, out);
}

// Round 2
// 1077.061 us; speedup vs baseline: 1.0938x; 1.0938x over previous
//
#include <hip/hip_runtime.h>

typedef __bf16 bf16_t;
typedef bf16_t bf16x8 __attribute__((ext_vector_type(8)));
typedef bf16_t bf16x4 __attribute__((ext_vector_type(4)));
typedef float  f32x4  __attribute__((ext_vector_type(4)));

typedef const __attribute__((address_space(1))) void* gptr_t;
typedef __attribute__((address_space(3))) void* sptr_t;

#define BATCH 8
#define SEQL  4096
#define DIM   1024
#define MROWS 32768

__device__ __forceinline__ float sigmoidf_(float v) {
    return 1.0f / (1.0f + __expf(-v));
}

// ---------------- transpose + cast fp32 (K,N) -> bf16 (N,K) ----------------
// PERM=1: permute output row n so GEMM3 tiles hold (ig,fg) pairs:
//   n<1024 (ig col d): dest = (d>>6)*128 + (d&63)
//   n>=1024 (fg col d): dest = (d>>6)*128 + 64 + (d&63)
template <int PERM>
__global__ void transpose_cast(const float* __restrict__ W, bf16_t* __restrict__ WT,
                               int K, int N) {
    __shared__ float s[32][33];
    int tx = threadIdx.x, ty = threadIdx.y;
    int x = blockIdx.x * 32 + tx;   // N index
    int y = blockIdx.y * 32 + ty;   // K index
    s[ty][tx] = W[(size_t)y * N + x];
    __syncthreads();
    int n = blockIdx.x * 32 + ty;
    int k = blockIdx.y * 32 + tx;
    int nd = n;
    if (PERM) {
        if (n < 1024) nd = ((n >> 6) << 7) + (n & 63);
        else          nd = (((n - 1024) >> 6) << 7) + 64 + ((n - 1024) & 63);
    }
    WT[(size_t)nd * K + k] = (bf16_t)s[tx][ty];
}

// ---------------- scan phase 1: per-chunk sums (full D per block) ----------
__global__ void scan_chunks(const float* __restrict__ x, float* __restrict__ cs) {
    int tid = threadIdx.x;
    int b = blockIdx.x >> 6, c = blockIdx.x & 63;
    const f32x4* x4 = (const f32x4*)x;
    size_t base = ((size_t)b * SEQL + (size_t)c * 64) * 256 + tid;
    f32x4 s0 = {0.f, 0.f, 0.f, 0.f}, s1 = {0.f, 0.f, 0.f, 0.f};
#pragma unroll 8
    for (int j = 0; j < 64; j += 2) {
        s0 += x4[base + (size_t)j * 256];
        s1 += x4[base + (size_t)(j + 1) * 256];
    }
    ((f32x4*)cs)[((size_t)(b << 6) + c) * 256 + tid] = s0 + s1;
}

// ---------------- scan phase 2: exclusive prefix over 64 chunks -------------
__global__ void scan_prefix(float* __restrict__ cs) {
    int t = blockIdx.x * 256 + threadIdx.x;   // 8192 threads
    int b = t >> 10, d = t & 1023;
    size_t base = (size_t)(b << 6) * 1024 + d;
    float v[64];
#pragma unroll
    for (int c = 0; c < 64; ++c) v[c] = cs[base + (size_t)c * 1024];
    float run = 0.f;
#pragma unroll
    for (int c = 0; c < 64; ++c) {
        float tv = v[c];
        cs[base + (size_t)c * 1024] = run;
        run += tv;
    }
}

// ---------------- scan phase 3 fused: avg + LayerNorm(bf16 h) + x cast ------
__global__ __launch_bounds__(256) void scan_ln(
    const float* __restrict__ x, const float* __restrict__ cs,
    const float* __restrict__ g, const float* __restrict__ bb,
    float* __restrict__ avg, bf16_t* __restrict__ hb, bf16_t* __restrict__ xb) {
    int tid = threadIdx.x;
    int wave = tid >> 6, lane = tid & 63;
    int b = blockIdx.x >> 6, c = blockIdx.x & 63;
    __shared__ float red[8];
    const f32x4* x4 = (const f32x4*)x;
    f32x4* avg4 = (f32x4*)avg;
    bf16x4* hb4 = (bf16x4*)hb;
    bf16x4* xb4 = (bf16x4*)xb;
    f32x4 run = ((const f32x4*)cs)[((size_t)(b << 6) + c) * 256 + tid];
    f32x4 gv = ((const f32x4*)g)[tid];
    f32x4 bv = ((const f32x4*)bb)[tid];
    size_t row0 = (size_t)b * SEQL + (size_t)c * 64;
    f32x4 xv = x4[row0 * 256 + tid];
    for (int j = 0; j < 64; ++j) {
        size_t ridx = (row0 + j) * 256 + tid;
        f32x4 xnext = {0.f, 0.f, 0.f, 0.f};
        if (j < 63) xnext = x4[ridx + 256];           // prefetch next row
        run += xv;
        float inv = 1.0f / (float)(c * 64 + j + 1);
        f32x4 av = run * inv;
        avg4[ridx] = av;
        bf16x4 xo = { (bf16_t)xv[0], (bf16_t)xv[1], (bf16_t)xv[2], (bf16_t)xv[3] };
        xb4[ridx] = xo;
        float s  = av[0] + av[1] + av[2] + av[3];
        float sq = av[0]*av[0] + av[1]*av[1] + av[2]*av[2] + av[3]*av[3];
#pragma unroll
        for (int off = 32; off; off >>= 1) {
            s  += __shfl_xor(s, off);
            sq += __shfl_xor(sq, off);
        }
        if (lane == 0) { red[wave] = s; red[4 + wave] = sq; }
        __syncthreads();
        s  = red[0] + red[1] + red[2] + red[3];
        sq = red[4] + red[5] + red[6] + red[7];
        float mu  = s * (1.f / DIM);
        float var = sq * (1.f / DIM) - mu * mu;
        var = var < 0.f ? 0.f : var;
        float rs = 1.0f / sqrtf(var + 1e-6f);
        f32x4 hn = (av - mu) * rs * gv + bv;
        bf16x4 ho = { (bf16_t)hn[0], (bf16_t)hn[1], (bf16_t)hn[2], (bf16_t)hn[3] };
        hb4[ridx] = ho;
        __syncthreads();   // red[] reused next iteration
        xv = xnext;
    }
}

// ---------------- MFMA bf16 GEMM, 128x128 tile, BK=64, XOR-swizzled LDS -----
// C = A @ Bt^T ; A row stride = kSplit; A source switches at k=kSplit.
// LDS layout: position (row, ch) holds global 16B-chunk (ch ^ (row&7)).
// EPI 1: outb = bf16(relu(acc + bias[n]))
// EPI 2: v = acc + bias[n] + addsrc; outf = v; outb = bf16(v)
// EPI 4: fused gating. N-cols are permuted (see transpose_cast<1>):
//        pos<64 -> ig col T*64+pos, pos>=64 -> fg col 1024+T*64+(pos-64).
//        out[row,d] = sig(ig)*xsrc + sig(fg)*addsrc, exchanged via LDS.
template <int EPI>
__global__ __launch_bounds__(256) void gemm_bt(
    const bf16_t* __restrict__ A0, const bf16_t* __restrict__ A1, int kSplit,
    const bf16_t* __restrict__ Bt, int N, int K,
    const float* __restrict__ bias, const float* __restrict__ addsrc,
    const float* __restrict__ xsrc,
    float* __restrict__ outf, bf16_t* __restrict__ outb) {
    __shared__ char smem[128 * 64 * 2 * 2];
    bf16_t* As = (bf16_t*)smem;
    bf16_t* Bs = (bf16_t*)(smem + 128 * 64 * 2);
    const int tid = threadIdx.x;
    const int wave = tid >> 6, lane = tid & 63;
    const int nBlocks = N >> 7;
    const int m0 = (int)(blockIdx.x / nBlocks) << 7;
    const int n0 = (int)(blockIdx.x % nBlocks) << 7;
    const int wm = (wave & 1) << 6;
    const int wn = (wave >> 1) << 6;
    const int lrow16 = lane & 15;
    // swizzled k-offsets (elements) for the two kk steps; row&7 == lane&7
    const int ksw0 = ((((lane >> 4) + 0) ^ (lane & 7)) << 3);
    const int ksw1 = ((((lane >> 4) + 4) ^ (lane & 7)) << 3);

    f32x4 acc[4][4] = {};

    for (int k0 = 0; k0 < K; k0 += 64) {
        __syncthreads();
        const bf16_t* Asrc;
        int ak0;
        if (k0 < kSplit) { Asrc = A0; ak0 = k0; }
        else             { Asrc = A1; ak0 = k0 - kSplit; }
#pragma unroll
        for (int rd = 0; rd < 4; ++rd) {
            int ci = tid + rd * 256;
            int row = ci >> 3, ch = ci & 7;
            int chs = ch ^ (row & 7);
            const bf16_t* gp = Asrc + (size_t)(m0 + row) * kSplit + ak0 + (chs << 3);
            bf16_t* sb = As + (size_t)(ci & ~63) * 8;
            __builtin_amdgcn_global_load_lds((gptr_t)gp, (sptr_t)sb, 16, 0, 0);
        }
#pragma unroll
        for (int rd = 0; rd < 4; ++rd) {
            int ci = tid + rd * 256;
            int row = ci >> 3, ch = ci & 7;
            int chs = ch ^ (row & 7);
            const bf16_t* gp = Bt + (size_t)(n0 + row) * K + k0 + (chs << 3);
            bf16_t* sb = Bs + (size_t)(ci & ~63) * 8;
            __builtin_amdgcn_global_load_lds((gptr_t)gp, (sptr_t)sb, 16, 0, 0);
        }
        __syncthreads();
#pragma unroll
        for (int kk = 0; kk < 2; ++kk) {
            const int ksw = kk ? ksw1 : ksw0;
            bf16x8 af[4], bfv[4];
#pragma unroll
            for (int mi = 0; mi < 4; ++mi)
                af[mi] = *(const bf16x8*)&As[(wm + mi * 16 + lrow16) * 64 + ksw];
#pragma unroll
            for (int ni = 0; ni < 4; ++ni)
                bfv[ni] = *(const bf16x8*)&Bs[(wn + ni * 16 + lrow16) * 64 + ksw];
#pragma unroll
            for (int mi = 0; mi < 4; ++mi)
#pragma unroll
                for (int ni = 0; ni < 4; ++ni)
                    acc[mi][ni] = __builtin_amdgcn_mfma_f32_16x16x32_bf16(
                        af[mi], bfv[ni], acc[mi][ni], 0, 0, 0);
        }
    }

    const int erow = (lane >> 4) << 2;

    if (EPI == 4) {
        __syncthreads();                    // all waves done with As/Bs
        float* xch = (float*)smem;          // [2][64][64] exchange buffer
        const int T = n0 >> 7;
        const int mloc = (wm >> 6) * 4096;
        if (wave >= 2) {                    // fg waves (wn=64)
#pragma unroll
            for (int mi = 0; mi < 4; ++mi) {
#pragma unroll
                for (int ni = 0; ni < 4; ++ni) {
                    int dc = ni * 16 + lrow16;            // 0..63
                    float bcol = bias[1024 + T * 64 + dc];
                    int d = T * 64 + dc;
#pragma unroll
                    for (int r = 0; r < 4; ++r) {
                        int row = m0 + wm + mi * 16 + erow + r;
                        float v = acc[mi][ni][r] + bcol;
                        float part = sigmoidf_(v) * addsrc[(size_t)row * 1024 + d];
                        xch[mloc + (mi * 16 + erow + r) * 64 + dc] = part;
                    }
                }
            }
        }
        __syncthreads();
        if (wave < 2) {                     // ig waves (wn=0)
#pragma unroll
            for (int mi = 0; mi < 4; ++mi) {
#pragma unroll
                for (int ni = 0; ni < 4; ++ni) {
                    int dc = ni * 16 + lrow16;            // 0..63
                    float bcol = bias[T * 64 + dc];
                    int d = T * 64 + dc;
#pragma unroll
                    for (int r = 0; r < 4; ++r) {
                        int row = m0 + wm + mi * 16 + erow + r;
                        float v = acc[mi][ni][r] + bcol;
                        float tot = sigmoidf_(v) * xsrc[(size_t)row * 1024 + d]
                                  + xch[mloc + (mi * 16 + erow + r) * 64 + dc];
                        outf[(size_t)row * 1024 + d] = tot;
                    }
                }
            }
        }
        return;
    }

#pragma unroll
    for (int mi = 0; mi < 4; ++mi) {
#pragma unroll
        for (int ni = 0; ni < 4; ++ni) {
            int col = n0 + wn + ni * 16 + lrow16;
            float bcol = bias[col];
#pragma unroll
            for (int r = 0; r < 4; ++r) {
                int row = m0 + wm + mi * 16 + erow + r;
                size_t idx = (size_t)row * N + col;
                float v = acc[mi][ni][r];
                if (EPI == 1) {
                    v += bcol;
                    v = v > 0.f ? v : 0.f;
                    outb[idx] = (bf16_t)v;
                } else {  // EPI == 2
                    v += bcol + addsrc[idx];
                    outf[idx] = v;
                    outb[idx] = (bf16_t)v;
                }
            }
        }
    }
}

// ---------------- launch ----------------
extern "C" void kernel_launch(void* const* d_in, const int* in_sizes, int n_in,
                              void* d_out, int out_size, void* d_ws, size_t ws_size,
                              hipStream_t stream) {
    const float* inp  = (const float*)d_in[0];
    const float* w1   = (const float*)d_in[1];
    const float* b1   = (const float*)d_in[2];
    const float* w2   = (const float*)d_in[3];
    const float* b2   = (const float*)d_in[4];
    const float* ln_g = (const float*)d_in[5];
    const float* ln_b = (const float*)d_in[6];
    const float* wg   = (const float*)d_in[7];
    const float* bg   = (const float*)d_in[8];
    float* out = (float*)d_out;

    char* w = (char*)d_ws;
    float*  avg    = (float*)w;   w += (size_t)MROWS * DIM * 4;       // 128 MB
    float*  avgout = (float*)w;   w += (size_t)MROWS * DIM * 4;       // 128 MB
    bf16_t* xb     = (bf16_t*)w;  w += (size_t)MROWS * DIM * 2;       // 64 MB
    bf16_t* hb     = (bf16_t*)w;  w += (size_t)MROWS * DIM * 2;       // 64 MB
    bf16_t* interb = (bf16_t*)w;  w += (size_t)MROWS * DIM * 2;       // 64 MB
    bf16_t* w1t    = (bf16_t*)w;  w += (size_t)DIM * DIM * 2;         // 2 MB
    bf16_t* w2t    = (bf16_t*)w;  w += (size_t)DIM * DIM * 2;         // 2 MB
    bf16_t* wgt    = (bf16_t*)w;  w += (size_t)2 * DIM * 2 * DIM * 2; // 8 MB
    float*  csum   = (float*)w;   w += (size_t)BATCH * 64 * DIM * 4;  // 2 MB
    bf16_t* aob    = hb;            // alias: h dead after GEMM1

    // weight transposes (fp32 KxN -> bf16 NxK); wg gets the ig/fg interleave
    transpose_cast<0><<<dim3(32, 32), dim3(32, 32), 0, stream>>>(w1, w1t, DIM, DIM);
    transpose_cast<0><<<dim3(32, 32), dim3(32, 32), 0, stream>>>(w2, w2t, DIM, DIM);
    transpose_cast<1><<<dim3(64, 64), dim3(32, 32), 0, stream>>>(wg, wgt, 2 * DIM, 2 * DIM);

    // prefix-mean scan + fused LN/cast
    scan_chunks<<<BATCH * 64, 256, 0, stream>>>(inp, csum);
    scan_prefix<<<32, 256, 0, stream>>>(csum);
    scan_ln<<<BATCH * 64, 256, 0, stream>>>(inp, csum, ln_g, ln_b, avg, hb, xb);

    // GEMM1: inter = relu(h @ w1 + b1)
    gemm_bt<1><<<(MROWS / 128) * (DIM / 128), 256, 0, stream>>>(
        hb, hb, DIM, w1t, DIM, DIM, b1, nullptr, nullptr, nullptr, interb);

    // GEMM2: avg_out = inter @ w2 + b2 + avg  (fp32 + bf16 stores)
    gemm_bt<2><<<(MROWS / 128) * (DIM / 128), 256, 0, stream>>>(
        interb, interb, DIM, w2t, DIM, DIM, b2, avg, nullptr, avgout, aob);

    // GEMM3 + gating fused: out = sig(ig)*x + sig(fg)*avg_out
    gemm_bt<4><<<(MROWS / 128) * (2 * DIM / 128), 256, 0, stream>>>(
        xb, aob, DIM, wgt, 2 * DIM, 2 * DIM, bg, avgout, inp, out, nullptr);
}